// Round 3
// baseline (9412.650 us; speedup 1.0000x reference)
//
#include <hip/hip_runtime.h>
#include <math.h>

#define T_STEPS 64
#define A_DIM   16
#define SEQ     1024      // T*A
#define HE      256       // encoder hidden per direction
#define DH      512       // decoder hidden
#define GE      1024      // 4*HE
#define GD      2048      // 4*DH

typedef _Float16 h2_t __attribute__((ext_vector_type(2)));

__device__ __forceinline__ float sigf(float x) { return 1.f / (1.f + __expf(-x)); }
// tanh via exp2-based __expf; args bounded here (|x| < ~4) so no overflow path.
__device__ __forceinline__ float tanh_fast(float x) {
    float e = __expf(-2.f * x);
    return (1.f - e) / (1.f + e);
}

__device__ __forceinline__ float fdot2f(h2_t a, h2_t b, float c) {
#if defined(__has_builtin) && __has_builtin(__builtin_amdgcn_fdot2)
    return __builtin_amdgcn_fdot2(a, b, c, false);
#else
    return c + (float)a.x * (float)b.x + (float)a.y * (float)b.y;
#endif
}

__device__ __forceinline__ float poll_comm(const float* p) {
    float v;
    do {
        v = __hip_atomic_load(p, __ATOMIC_RELAXED, __HIP_MEMORY_SCOPE_AGENT);
    } while (v == 0.f);
    return v - 4.0f;
}

__device__ __forceinline__ void post_comm(float* p, float h) {
    __hip_atomic_store(p, h + 4.0f, __ATOMIC_RELAXED, __HIP_MEMORY_SCOPE_AGENT);
}

// ---------------------------------------------------------------------------
// Embedding / decoder-input assembly
// ---------------------------------------------------------------------------
__global__ void k_embed(const int* __restrict__ lattice, const int* __restrict__ inputs,
                        const int* __restrict__ gold, const int* __restrict__ sos,
                        const float* __restrict__ lat_emb, const float* __restrict__ in_emb,
                        float* __restrict__ x, float* __restrict__ decin)
{
    int idx = blockIdx.x * 256 + threadIdx.x;
    if (idx < SEQ * 256) {
        int row = idx >> 8, e = idx & 255;
        int f = e >> 6, eo = e & 63;
        int id = lattice[row * 4 + f];
        x[idx] = lat_emb[id * 64 + eo];
    } else {
        int k = idx - SEQ * 256;
        if (k < T_STEPS * 512) {
            int t = k >> 9, d = k & 511;
            float val;
            if (d < 256) {
                int f = d >> 6, eo = d & 63;
                int id = (t == 0) ? sos[f]
                                  : lattice[(((t - 1) * A_DIM) + gold[t - 1]) * 4 + f];
                val = lat_emb[id * 64 + eo];
            } else {
                val = in_emb[inputs[t] * 256 + (d - 256)];
            }
            decin[k] = val;
        }
    }
}

// ---------------------------------------------------------------------------
// Generic fp32 GEMM: C[m,n] = bias[n] + sum_k A[m*lda+k] * B[n*ldbn + k*ldbk]
// ---------------------------------------------------------------------------
__global__ __launch_bounds__(256) void k_gemm(
    const float* __restrict__ A, int lda, long sA,
    const float* __restrict__ B, int ldbn, int ldbk, long sB,
    const float* __restrict__ bias, int sBias,
    float* __restrict__ C, int ldc, long sC,
    int M, int N, int K)
{
    int b = blockIdx.z;
    A += b * sA; B += b * sB; C += b * sC;
    if (bias) bias += (long)b * sBias;
    int n0 = blockIdx.x * 64, m0 = blockIdx.y * 64;
    __shared__ float As[64][17];
    __shared__ float Bs[64][17];
    int tid = threadIdx.x;
    int tn = tid & 15, tm = tid >> 4;
    float acc[4][4] = {};
    int lk = tid & 15, lr = tid >> 4;
    for (int k0 = 0; k0 < K; k0 += 16) {
#pragma unroll
        for (int i = 0; i < 4; i++) {
            int row = lr + i * 16;
            int am = m0 + row;
            As[row][lk] = (am < M) ? A[(long)am * lda + k0 + lk] : 0.f;
            int bn = n0 + row;
            Bs[row][lk] = (bn < N) ? B[(long)bn * ldbn + (long)(k0 + lk) * ldbk] : 0.f;
        }
        __syncthreads();
#pragma unroll
        for (int k = 0; k < 16; k++) {
            float av[4], bv[4];
#pragma unroll
            for (int i = 0; i < 4; i++) av[i] = As[tm * 4 + i][k];
#pragma unroll
            for (int j = 0; j < 4; j++) bv[j] = Bs[tn * 4 + j][k];
#pragma unroll
            for (int i = 0; i < 4; i++)
#pragma unroll
                for (int j = 0; j < 4; j++) acc[i][j] += av[i] * bv[j];
        }
        __syncthreads();
    }
#pragma unroll
    for (int i = 0; i < 4; i++) {
        int m = m0 + tm * 4 + i;
        if (m >= M) continue;
#pragma unroll
        for (int j = 0; j < 4; j++) {
            int n = n0 + tn * 4 + j;
            if (n < N) C[(long)m * ldc + n] = acc[i][j] + (bias ? bias[n] : 0.f);
        }
    }
}

// ---------------------------------------------------------------------------
// Encoder biLSTM recurrence, one layer. ONE BLOCK PER DIRECTION (512 thr):
// all sync is __syncthreads, no global comm. Thread (j=tid&255, half=tid>>8)
// holds 2 gate rows' f16 weights in VGPRs (asm-pinned so the compiler cannot
// sink the loads back into the K-loop — R2's VGPR_Count=100 proved it does).
// ---------------------------------------------------------------------------
__global__ __launch_bounds__(512, 1) void k_rec_enc(
    const float* __restrict__ pre,   // [2][SEQ][GE]
    const float* __restrict__ Whh,   // [2][GE][HE]
    float* __restrict__ y,           // [SEQ][512]
    float* __restrict__ hfin,        // [512] this layer's slot
    float* __restrict__ cfin)        // [512]
{
    const int tid = threadIdx.x;
    const int dir = blockIdx.x;
    const bool fwd = (dir == 0);
    const int j = tid & 255;
    const int half = tid >> 8;
    const int row_a = half * 256 + j;        // gate i (half0) / f (half1)
    const int row_b = row_a + 512;           // gate g (half0) / o (half1)
    const float* pre_d = pre + (long)dir * SEQ * GE;

    h2_t wa[128], wb[128];
    {
        const float4* ra = (const float4*)(Whh + (long)dir * GE * HE + (long)row_a * HE);
        const float4* rb = (const float4*)(Whh + (long)dir * GE * HE + (long)row_b * HE);
#pragma unroll
        for (int i = 0; i < 64; i++) {
            float4 va = ra[i], vb = rb[i];
            wa[2 * i]     = h2_t{(_Float16)va.x, (_Float16)va.y};
            wa[2 * i + 1] = h2_t{(_Float16)va.z, (_Float16)va.w};
            wb[2 * i]     = h2_t{(_Float16)vb.x, (_Float16)vb.y};
            wb[2 * i + 1] = h2_t{(_Float16)vb.z, (_Float16)vb.w};
        }
#pragma unroll
        for (int i = 0; i < 128; i++) {
            asm volatile("" : "+v"(wa[i]));
            asm volatile("" : "+v"(wb[i]));
        }
    }

    __shared__ __align__(16) _Float16 hsArr[HE];
    __shared__ float gl[GE];
    if (tid < 256) hsArr[tid] = (_Float16)0.f;
    __syncthreads();

    float c = 0.f, h_cur = 0.f;
    const int t0 = fwd ? 0 : SEQ - 1;
    float pa = pre_d[(long)t0 * GE + row_a];
    float pb = pre_d[(long)t0 * GE + row_b];

    for (int s = 0; s < SEQ; s++) {
        const int t = fwd ? s : SEQ - 1 - s;
        float a0 = 0, a1 = 0, b0 = 0, b1 = 0;
        const float4* hv = (const float4*)hsArr;
#pragma unroll
        for (int kk = 0; kk < 32; kk++) {
            float4 blk = hv[kk];
            const h2_t* hp = (const h2_t*)&blk;
            a0 = fdot2f(wa[4 * kk + 0], hp[0], a0);
            a1 = fdot2f(wa[4 * kk + 1], hp[1], a1);
            a0 = fdot2f(wa[4 * kk + 2], hp[2], a0);
            a1 = fdot2f(wa[4 * kk + 3], hp[3], a1);
            b0 = fdot2f(wb[4 * kk + 0], hp[0], b0);
            b1 = fdot2f(wb[4 * kk + 1], hp[1], b1);
            b0 = fdot2f(wb[4 * kk + 2], hp[2], b0);
            b1 = fdot2f(wb[4 * kk + 3], hp[3], b1);
        }
        gl[row_a] = pa + (a0 + a1);
        gl[row_b] = pb + (b0 + b1);
        if (s + 1 < SEQ) {
            int tn = fwd ? t + 1 : t - 1;
            pa = pre_d[(long)tn * GE + row_a];
            pb = pre_d[(long)tn * GE + row_b];
        }
        __syncthreads();
        if (tid < 256) {
            float gi = gl[j], gf = gl[256 + j], gg = gl[512 + j], go = gl[768 + j];
            c = sigf(gf) * c + sigf(gi) * tanh_fast(gg);
            h_cur = sigf(go) * tanh_fast(c);
            hsArr[j] = (_Float16)h_cur;
            y[(long)t * 512 + dir * 256 + j] = h_cur;
        }
        __syncthreads();
    }
    if (tid < 256) {
        hfin[dir * 256 + j] = h_cur;
        cfin[dir * 256 + j] = c;
    }
}

// ---------------------------------------------------------------------------
// Decoder LSTM recurrence, one layer. 4 blocks x 512 threads. Block b OWNS
// h-slice [b*128, b*128+128): computes all 4 gates for it locally (K split
// across thread pairs), publishes 128 h/step, polls 384. Weights asm-pinned.
// ---------------------------------------------------------------------------
__global__ __launch_bounds__(512, 1) void k_rec_dec(
    const float* __restrict__ pre,    // [64][GD]
    const float* __restrict__ Whh,    // [GD][DH] (layer-selected)
    const float* __restrict__ hinit,  // [512]
    const float* __restrict__ cinit,  // [512]
    float* __restrict__ hseq,         // [64][512]
    float* __restrict__ comm)         // [64][512], zeroed before launch
{
    const int tid = threadIdx.x, b = blockIdx.x;
    const int jj = tid & 127;
    const int p = tid >> 7;              // 0..3
    const int half = p & 1, gb = p >> 1; // gb in {0,1}; rows for gates gb, gb+2
    const int j_own = b * 128 + jj;
    const int r1 = gb * 512 + j_own;
    const int r2 = (gb + 2) * 512 + j_own;
    const int k0 = half * 256;

    h2_t w1[128], w2[128];
    {
        const float4* ra = (const float4*)(Whh + (long)r1 * DH + k0);
        const float4* rb = (const float4*)(Whh + (long)r2 * DH + k0);
#pragma unroll
        for (int i = 0; i < 64; i++) {
            float4 va = ra[i], vb = rb[i];
            w1[2 * i]     = h2_t{(_Float16)va.x, (_Float16)va.y};
            w1[2 * i + 1] = h2_t{(_Float16)va.z, (_Float16)va.w};
            w2[2 * i]     = h2_t{(_Float16)vb.x, (_Float16)vb.y};
            w2[2 * i + 1] = h2_t{(_Float16)vb.z, (_Float16)vb.w};
        }
#pragma unroll
        for (int i = 0; i < 128; i++) {
            asm volatile("" : "+v"(w1[i]));
            asm volatile("" : "+v"(w2[i]));
        }
    }

    __shared__ __align__(16) _Float16 hsArr[DH];
    __shared__ float part[1024];         // [(g*2+half)*128 + jj]
    hsArr[tid] = (_Float16)hinit[tid];
    float c = (tid < 128) ? cinit[j_own] : 0.f;
    float h_cur = 0.f;
    float p0 = 0.f, p1 = 0.f, p2 = 0.f, p3 = 0.f;
    if (tid < 128) {
        p0 = pre[0 * 512 + j_own];
        p1 = pre[1 * 512 + j_own];
        p2 = pre[2 * 512 + j_own];
        p3 = pre[3 * 512 + j_own];
    }
    __syncthreads();

    for (int s = 0; s < T_STEPS; s++) {
        float a0 = 0, a1 = 0, b0 = 0, b1 = 0;
        const float4* hv = (const float4*)(hsArr + k0);
#pragma unroll
        for (int kk = 0; kk < 32; kk++) {
            float4 blk = hv[kk];
            const h2_t* hp = (const h2_t*)&blk;
            a0 = fdot2f(w1[4 * kk + 0], hp[0], a0);
            a1 = fdot2f(w1[4 * kk + 1], hp[1], a1);
            a0 = fdot2f(w1[4 * kk + 2], hp[2], a0);
            a1 = fdot2f(w1[4 * kk + 3], hp[3], a1);
            b0 = fdot2f(w2[4 * kk + 0], hp[0], b0);
            b1 = fdot2f(w2[4 * kk + 1], hp[1], b1);
            b0 = fdot2f(w2[4 * kk + 2], hp[2], b0);
            b1 = fdot2f(w2[4 * kk + 3], hp[3], b1);
        }
        part[(gb * 2 + half) * 128 + jj]       = a0 + a1;
        part[((gb + 2) * 2 + half) * 128 + jj] = b0 + b1;
        __syncthreads();
        if (tid < 128) {
            float gi = part[0 * 128 + jj] + part[1 * 128 + jj] + p0;
            float gf = part[2 * 128 + jj] + part[3 * 128 + jj] + p1;
            float gg = part[4 * 128 + jj] + part[5 * 128 + jj] + p2;
            float go = part[6 * 128 + jj] + part[7 * 128 + jj] + p3;
            if (s + 1 < T_STEPS) {
                p0 = pre[(long)(s + 1) * GD + 0 * 512 + j_own];
                p1 = pre[(long)(s + 1) * GD + 1 * 512 + j_own];
                p2 = pre[(long)(s + 1) * GD + 2 * 512 + j_own];
                p3 = pre[(long)(s + 1) * GD + 3 * 512 + j_own];
            }
            c = sigf(gf) * c + sigf(gi) * tanh_fast(gg);
            h_cur = sigf(go) * tanh_fast(c);
            post_comm(&comm[(long)s * DH + j_own], h_cur);
            hseq[(long)s * DH + j_own] = h_cur;
            hsArr[j_own] = (_Float16)h_cur;
        } else if (s + 1 < T_STEPS) {
            int idx = (b * 128 + 128 + (tid - 128)) & 511;   // the 384 remote
            hsArr[idx] = (_Float16)poll_comm(&comm[(long)s * DH + idx]);
        }
        __syncthreads();
    }
}

// ---------------------------------------------------------------------------
// Attention readout
// ---------------------------------------------------------------------------
__global__ void k_attn(const float* __restrict__ encK, const float* __restrict__ qs,
                       const float* __restrict__ v, const int* __restrict__ alens,
                       float* __restrict__ out)
{
    int t = blockIdx.x;
    int tid = threadIdx.x;
    int wave = tid >> 6, lane = tid & 63;
    int len = alens[t];
    const float* qt = qs + t * 256;
    for (int a = wave; a < A_DIM; a += 4) {
        const float* ek = encK + (long)(t * A_DIM + a) * 256;
        float sum = 0.f;
#pragma unroll
        for (int e = 0; e < 4; e++) {
            int d = lane * 4 + e;
            sum += v[d] * tanhf(ek[d] + qt[d]);
        }
        for (int off = 32; off; off >>= 1) sum += __shfl_down(sum, off, 64);
        if (lane == 0) out[t * A_DIM + a] = (a < len) ? sum : -1e10f;
    }
}

// ---------------------------------------------------------------------------
extern "C" void kernel_launch(void* const* d_in, const int* in_sizes, int n_in,
                              void* d_out, int out_size, void* d_ws, size_t ws_size,
                              hipStream_t stream)
{
    (void)in_sizes; (void)n_in; (void)out_size; (void)ws_size;
    const int*   lattice = (const int*)d_in[0];
    const int*   alens   = (const int*)d_in[1];
    const int*   inputs  = (const int*)d_in[2];
    const int*   gold    = (const int*)d_in[4];
    const int*   sos     = (const int*)d_in[5];
    const float* lat_emb = (const float*)d_in[6];
    const float* in_emb  = (const float*)d_in[7];
    const float* Wih0    = (const float*)d_in[8];
    const float* Whh0    = (const float*)d_in[9];
    const float* b0      = (const float*)d_in[10];
    const float* Wih1    = (const float*)d_in[11];
    const float* Whh1    = (const float*)d_in[12];
    const float* b1      = (const float*)d_in[13];
    const float* dWih    = (const float*)d_in[14];
    const float* dWhh    = (const float*)d_in[15];
    const float* db      = (const float*)d_in[16];
    const float* Wq      = (const float*)d_in[17];
    const float* Wk      = (const float*)d_in[18];
    const float* av      = (const float*)d_in[19];
    float* out = (float*)d_out;
    float* ws  = (float*)d_ws;

    // ws layout (floats) — total 3,459,072 floats = 13.8 MB
    float* commD = ws;                  // 65536   [2 layers][64][512]
    float* xbuf  = ws + 65536;          // 262144
    float* pre   = ws + 327680;         // 2097152
    float* y0    = ws + 2424832;        // 524288  (layer outputs; L1 overwrites)
    float* hdec  = ws + 2949120;        // 1024    [2][512]
    float* cdec  = ws + 2950144;        // 1024
    float* decin = ws + 2951168;        // 32768   [64][512]
    float* encK  = ws + 2983936;        // 262144
    float* dpre  = ws + 3246080;        // 131072
    float* h0seq = ws + 3377152;        // 32768
    float* h1seq = ws + 3409920;        // 32768
    float* qseq  = ws + 3442688;        // 16384

    // zero decoder comm buffers (ws poisoned 0xAA before every launch)
    hipMemsetAsync(commD, 0, 65536 * sizeof(float), stream);

    k_embed<<<1152, 256, 0, stream>>>(lattice, inputs, gold, sos, lat_emb, in_emb, xbuf, decin);

    // pre = x @ Wih0^T + b0  (both dirs batched)
    k_gemm<<<dim3(16, 16, 2), 256, 0, stream>>>(
        xbuf, 256, 0L, Wih0, 256, 1, (long)GE * 256, b0, GE,
        pre, GE, (long)SEQ * GE, SEQ, GE, 256);
    k_rec_enc<<<2, 512, 0, stream>>>(pre, Whh0, y0, hdec, cdec);

    // pre = y0 @ Wih1^T + b1
    k_gemm<<<dim3(16, 16, 2), 256, 0, stream>>>(
        y0, 512, 0L, Wih1, 512, 1, (long)GE * 512, b1, GE,
        pre, GE, (long)SEQ * GE, SEQ, GE, 512);
    k_rec_enc<<<2, 512, 0, stream>>>(pre, Whh1, y0, hdec + 512, cdec + 512);

    // encK = enc @ Wk
    k_gemm<<<dim3(4, 16, 1), 256, 0, stream>>>(
        y0, 512, 0L, Wk, 1, 256, 0L, nullptr, 0,
        encK, 256, 0L, SEQ, 256, 512);

    // dpre = decin @ dWih[0]^T + db[0]
    k_gemm<<<dim3(32, 1, 1), 256, 0, stream>>>(
        decin, 512, 0L, dWih, 512, 1, 0L, db, 0,
        dpre, GD, 0L, T_STEPS, GD, 512);
    k_rec_dec<<<4, 512, 0, stream>>>(dpre, dWhh, hdec, cdec, h0seq, commD);

    // dpre = h0seq @ dWih[1]^T + db[1]
    k_gemm<<<dim3(32, 1, 1), 256, 0, stream>>>(
        h0seq, 512, 0L, dWih + (long)GD * 512, 512, 1, 0L, db + GD, 0,
        dpre, GD, 0L, T_STEPS, GD, 512);
    k_rec_dec<<<4, 512, 0, stream>>>(dpre, dWhh + (long)GD * 512, hdec + 512, cdec + 512,
                                     h1seq, commD + 32768);

    // q = h1seq @ Wq
    k_gemm<<<dim3(4, 1, 1), 256, 0, stream>>>(
        h1seq, 512, 0L, Wq, 1, 256, 0L, nullptr, 0,
        qseq, 256, 0L, T_STEPS, 256, 512);

    k_attn<<<64, 256, 0, stream>>>(encK, qseq, av, alens, out);
}